// Round 2
// baseline (403.010 us; speedup 1.0000x reference)
//
#include <hip/hip_runtime.h>
#include <math.h>

// keys [B,S,H] f32, query [B,H] f32, t unused.
// d_out = attn_values [B,H] (32768 f32) ++ attn [B,S,1] (65536 f32).
constexpr int B = 32, S = 2048, H = 1024;
constexpr float SCALE = 0.03125f;   // 1/sqrt(1024)

constexpr int NC1 = 32;                       // s-chunks per batch (K1)
constexpr int ROWS_PER_BLOCK = S / NC1;       // 64
constexpr int ROWS_PER_WAVE  = ROWS_PER_BLOCK / 4;  // 16

constexpr int ND4 = 16;                       // d-slices of 64 cols (K4)

// ws (floats): ml [B*NC1*2] = 2048, MLg [B*2] = 64  -> 8448 bytes total.
constexpr size_t WS_ML  = 0;
constexpr size_t WS_MLG = WS_ML + (size_t)B * NC1 * 2;

__device__ __forceinline__ float dot4(const float4 a, const float4 q) {
  return a.x * q.x + a.y * q.y + a.z * q.z + a.w * q.w;
}

// K1: raw scaled scores -> out_attn; per-chunk (m, l) -> ws.
// One block per (b, 64-row chunk); one wave per 16 rows; lane owns 16 d-cols.
__global__ __launch_bounds__(256) void k1_scores(
    const float* __restrict__ keys, const float* __restrict__ query,
    float* __restrict__ out_attn, float* __restrict__ ws) {
  const int b = blockIdx.x / NC1;
  const int c = blockIdx.x % NC1;
  const int t = threadIdx.x;
  const int wave = t >> 6, lane = t & 63;
  const int srow0 = c * ROWS_PER_BLOCK + wave * ROWS_PER_WAVE;

  const float* kb = keys + (size_t)b * S * H;
  const float* qb = query + (size_t)b * H;

  const float4 q0 = *(const float4*)(qb + 0 * 256 + lane * 4);
  const float4 q1 = *(const float4*)(qb + 1 * 256 + lane * 4);
  const float4 q2 = *(const float4*)(qb + 2 * 256 + lane * 4);
  const float4 q3 = *(const float4*)(qb + 3 * 256 + lane * 4);

  float m = -INFINITY, l = 0.f;

  for (int s = srow0; s < srow0 + ROWS_PER_WAVE; s += 2) {
    const float* r0 = kb + (size_t)s * H;
    const float* r1 = kb + (size_t)(s + 1) * H;
    const float4 a0 = *(const float4*)(r0 + 0 * 256 + lane * 4);
    const float4 a1 = *(const float4*)(r0 + 1 * 256 + lane * 4);
    const float4 a2 = *(const float4*)(r0 + 2 * 256 + lane * 4);
    const float4 a3 = *(const float4*)(r0 + 3 * 256 + lane * 4);
    const float4 b0 = *(const float4*)(r1 + 0 * 256 + lane * 4);
    const float4 b1 = *(const float4*)(r1 + 1 * 256 + lane * 4);
    const float4 b2 = *(const float4*)(r1 + 2 * 256 + lane * 4);
    const float4 b3 = *(const float4*)(r1 + 3 * 256 + lane * 4);

    float d0 = dot4(a0, q0) + dot4(a1, q1) + dot4(a2, q2) + dot4(a3, q3);
    float d1 = dot4(b0, q0) + dot4(b1, q1) + dot4(b2, q2) + dot4(b3, q3);
#pragma unroll
    for (int off = 1; off < 64; off <<= 1) {
      d0 += __shfl_xor(d0, off);
      d1 += __shfl_xor(d1, off);
    }
    d0 *= SCALE;
    d1 *= SCALE;
    if (lane == 0) {
      out_attn[(size_t)b * S + s]     = d0;
      out_attn[(size_t)b * S + s + 1] = d1;
    }
    const float mn = fmaxf(m, fmaxf(d0, d1));
    l = l * __expf(m - mn) + __expf(d0 - mn) + __expf(d1 - mn);
    m = mn;
  }

  __shared__ float wm[4], wl[4];
  if (lane == 0) { wm[wave] = m; wl[wave] = l; }
  __syncthreads();
  if (t == 0) {
    const float M = fmaxf(fmaxf(wm[0], wm[1]), fmaxf(wm[2], wm[3]));
    const float L = wl[0] * __expf(wm[0] - M) + wl[1] * __expf(wm[1] - M) +
                    wl[2] * __expf(wm[2] - M) + wl[3] * __expf(wm[3] - M);
    float* ml = ws + WS_ML;
    ml[((size_t)b * NC1 + c) * 2 + 0] = M;
    ml[((size_t)b * NC1 + c) * 2 + 1] = L;
  }
}

// K2: merge per-chunk (m,l) -> per-batch (M,L). One wave per batch.
__global__ __launch_bounds__(64) void k2_merge(float* __restrict__ ws) {
  const int b = blockIdx.x;
  const int lane = threadIdx.x;
  const float* ml = ws + WS_ML;
  float m = -INFINITY, l = 0.f;
  if (lane < NC1) {
    m = ml[((size_t)b * NC1 + lane) * 2 + 0];
    l = ml[((size_t)b * NC1 + lane) * 2 + 1];
  }
  float M = m;
#pragma unroll
  for (int off = 1; off < 64; off <<= 1) M = fmaxf(M, __shfl_xor(M, off));
  float e = l * __expf(m - M);  // inactive lanes: 0 * 0 = 0
#pragma unroll
  for (int off = 1; off < 64; off <<= 1) e += __shfl_xor(e, off);
  if (lane == 0) {
    ws[WS_MLG + b * 2 + 0] = M;
    ws[WS_MLG + b * 2 + 1] = e;
  }
}

// K3: in-place transform raw scores -> softmax weights.
__global__ __launch_bounds__(256) void k3_weights(
    float* __restrict__ out_attn, const float* __restrict__ ws) {
  const int i = blockIdx.x * 256 + threadIdx.x;  // b uniform per block (2048%256==0)
  const int b = i >> 11;
  const float M = ws[WS_MLG + b * 2 + 0];
  const float invL = 1.0f / ws[WS_MLG + b * 2 + 1];
  out_attn[i] = __expf(out_attn[i] - M) * invL;
}

// K4: attn_values[b,:] = sum_s attn[b,s] * keys[b,s,:].
// One block per (b, 64-col slice); wave r handles rows s ≡ r (mod 4).
__global__ __launch_bounds__(256) void k4_values(
    const float* __restrict__ keys, const float* __restrict__ attn,
    float* __restrict__ out_values) {
  const int b   = blockIdx.x / ND4;
  const int dsl = blockIdx.x % ND4;
  const int t = threadIdx.x;
  const int r = t >> 6;        // 0..3 == wave index (row phase)
  const int cc = t & 63;
  const float* kb = keys + (size_t)b * S * H + (size_t)dsl * 64 + cc;
  const float* ab = attn + (size_t)b * S;

  float acc = 0.f;
  for (int s0 = r; s0 < S; s0 += 64) {  // 16 strided rows per iteration
    float kv[16], av[16];
#pragma unroll
    for (int u = 0; u < 16; ++u) {
      const int s = s0 + 4 * u;
      kv[u] = kb[(size_t)s * H];
      av[u] = ab[s];
    }
#pragma unroll
    for (int u = 0; u < 16; ++u) acc = fmaf(av[u], kv[u], acc);
  }

  __shared__ float part[4][64];
  part[r][cc] = acc;
  __syncthreads();
  if (t < 64) {
    const float v = part[0][t] + part[1][t] + part[2][t] + part[3][t];
    out_values[(size_t)b * H + (size_t)dsl * 64 + t] = v;
  }
}

extern "C" void kernel_launch(void* const* d_in, const int* in_sizes, int n_in,
                              void* d_out, int out_size, void* d_ws, size_t ws_size,
                              hipStream_t stream) {
  const float* keys  = (const float*)d_in[0];
  const float* query = (const float*)d_in[1];
  float* out = (float*)d_out;
  float* ws  = (float*)d_ws;

  float* out_values = out;                  // [B, H]
  float* out_attn   = out + (size_t)B * H;  // [B, S, 1]

  k1_scores<<<B * NC1, 256, 0, stream>>>(keys, query, out_attn, ws);
  k2_merge<<<B, 64, 0, stream>>>(ws);
  k3_weights<<<(B * S) / 256, 256, 0, stream>>>(out_attn, ws);
  k4_values<<<B * ND4, 256, 0, stream>>>(keys, out_attn, out_values);
}

// Round 3
// 369.823 us; speedup vs baseline: 1.0897x; 1.0897x over previous
//
#include <hip/hip_runtime.h>
#include <math.h>

// keys [B,S,H] f32, query [B,H] f32, t unused.
// d_out = attn_values [B,H] (32768 f32) ++ attn [B,S,1] (65536 f32).
constexpr int B = 32, S = 2048, H = 1024;
constexpr float SCALE = 0.03125f;   // 1/sqrt(1024)

// ---------- fast path (single read of keys) ----------
constexpr int NC = 32;              // s-chunks per batch
constexpr int SC = S / NC;          // 64 rows per chunk-block
constexpr int TILE = 8;             // rows per inner iteration

// ws layout (floats): ml [B*NC*2] | MLg [B*2] | o_chunks [B*NC*H]
constexpr size_t WS_ML  = 0;
constexpr size_t WS_MLG = WS_ML + (size_t)B * NC * 2;
constexpr size_t WS_O   = WS_MLG + (size_t)B * 2;
constexpr size_t WS_NEEDED_BYTES = (WS_O + (size_t)B * NC * H) * sizeof(float);

// One block per (b, chunk). Single pass over the chunk's keys: raw scores ->
// out_attn, online-softmax (m,l) + weighted key-sum partial -> ws.
// Thread t owns d-cols [4t, 4t+4).
__global__ __launch_bounds__(256) void k1_fused(
    const float* __restrict__ keys, const float* __restrict__ query,
    float* __restrict__ out_attn, float* __restrict__ ws) {
  const int b = blockIdx.x / NC;
  const int c = blockIdx.x % NC;
  const int t = threadIdx.x;
  const int d0 = t * 4;
  const int wave = t >> 6, lane = t & 63;

  float* ml       = ws + WS_ML;
  float* o_chunks = ws + WS_O;

  const float* kb = keys + (size_t)b * S * H + (size_t)c * SC * H;
  const float4 q = *(const float4*)(query + (size_t)b * H + d0);

  float m = -INFINITY, l = 0.0f;
  float o0 = 0.f, o1 = 0.f, o2 = 0.f, o3 = 0.f;

  __shared__ float red[4][TILE];

  for (int s0 = 0; s0 < SC; s0 += TILE) {
    float4 k[TILE];
    float p[TILE];
#pragma unroll
    for (int j = 0; j < TILE; ++j) {
      k[j] = *(const float4*)(kb + (size_t)(s0 + j) * H + d0);
      p[j] = k[j].x * q.x + k[j].y * q.y + k[j].z * q.z + k[j].w * q.w;
    }
#pragma unroll
    for (int off = 32; off > 0; off >>= 1) {
#pragma unroll
      for (int j = 0; j < TILE; ++j) p[j] += __shfl_down(p[j], off);
    }
    if (lane == 0) {
#pragma unroll
      for (int j = 0; j < TILE; ++j) red[wave][j] = p[j];
    }
    __syncthreads();
    float snew[TILE];
    float mt = m;
#pragma unroll
    for (int j = 0; j < TILE; ++j) {
      snew[j] = (red[0][j] + red[1][j] + red[2][j] + red[3][j]) * SCALE;
      mt = fmaxf(mt, snew[j]);
    }
    // raw scores straight into the attn output region
    if (t < TILE) out_attn[(size_t)b * S + c * SC + s0 + t] = snew[t];

    const float alpha = __expf(m - mt);
    float w[TILE];
    float lsum = 0.f;
#pragma unroll
    for (int j = 0; j < TILE; ++j) { w[j] = __expf(snew[j] - mt); lsum += w[j]; }
    l = l * alpha + lsum;
    o0 *= alpha; o1 *= alpha; o2 *= alpha; o3 *= alpha;
#pragma unroll
    for (int j = 0; j < TILE; ++j) {
      o0 += w[j] * k[j].x;
      o1 += w[j] * k[j].y;
      o2 += w[j] * k[j].z;
      o3 += w[j] * k[j].w;
    }
    m = mt;
    __syncthreads();
  }

  *(float4*)(o_chunks + ((size_t)b * NC + c) * H + d0) =
      make_float4(o0, o1, o2, o3);
  if (t == 0) {
    ml[((size_t)b * NC + c) * 2 + 0] = m;
    ml[((size_t)b * NC + c) * 2 + 1] = l;
  }
}

// One block per batch: merge NC partials -> attn_values; store (M,L).
__global__ __launch_bounds__(256) void k2_combine(
    float* __restrict__ ws, float* __restrict__ out_values) {
  const int b = blockIdx.x;
  const int t = threadIdx.x;
  const int d0 = t * 4;

  const float* ml       = ws + WS_ML;
  const float* o_chunks = ws + WS_O;

  float M = -INFINITY;
#pragma unroll 4
  for (int c = 0; c < NC; ++c)
    M = fmaxf(M, ml[((size_t)b * NC + c) * 2 + 0]);
  float L = 0.f;
#pragma unroll 4
  for (int c = 0; c < NC; ++c) {
    const float mc = ml[((size_t)b * NC + c) * 2 + 0];
    const float lc = ml[((size_t)b * NC + c) * 2 + 1];
    L += lc * __expf(mc - M);
  }
  float a0 = 0.f, a1 = 0.f, a2 = 0.f, a3 = 0.f;
  for (int c = 0; c < NC; ++c) {
    const float mc = ml[((size_t)b * NC + c) * 2 + 0];
    const float wgt = __expf(mc - M);
    const float4 oc = *(const float4*)(o_chunks + ((size_t)b * NC + c) * H + d0);
    a0 += wgt * oc.x; a1 += wgt * oc.y; a2 += wgt * oc.z; a3 += wgt * oc.w;
  }
  const float inv = 1.0f / L;
  *(float4*)(out_values + (size_t)b * H + d0) =
      make_float4(a0 * inv, a1 * inv, a2 * inv, a3 * inv);
  if (t == 0) {
    ws[WS_MLG + b * 2 + 0] = M;
    ws[WS_MLG + b * 2 + 1] = L;
  }
}

// Normalize raw scores in-place -> softmax weights.
__global__ __launch_bounds__(256) void k3_norm(
    float* __restrict__ out_attn, const float* __restrict__ ws) {
  const int i = blockIdx.x * 256 + threadIdx.x;
  const int b = i >> 11;  // S = 2048
  const float M = ws[WS_MLG + b * 2 + 0];
  const float invL = 1.0f / ws[WS_MLG + b * 2 + 1];
  out_attn[i] = __expf(out_attn[i] - M) * invL;
}

// ---------- fallback path (proven round-2 two-pass; tiny ws) ----------
constexpr int ROWS_PER_BLOCK = SC;                 // 64
constexpr int ROWS_PER_WAVE  = ROWS_PER_BLOCK / 4; // 16
constexpr int ND4 = 16;

__device__ __forceinline__ float dot4(const float4 a, const float4 q) {
  return a.x * q.x + a.y * q.y + a.z * q.z + a.w * q.w;
}

__global__ __launch_bounds__(256) void k1b_scores(
    const float* __restrict__ keys, const float* __restrict__ query,
    float* __restrict__ out_attn, float* __restrict__ ws) {
  const int b = blockIdx.x / NC;
  const int c = blockIdx.x % NC;
  const int t = threadIdx.x;
  const int wave = t >> 6, lane = t & 63;
  const int srow0 = c * ROWS_PER_BLOCK + wave * ROWS_PER_WAVE;

  const float* kb = keys + (size_t)b * S * H;
  const float* qb = query + (size_t)b * H;
  const float4 q0 = *(const float4*)(qb + 0 * 256 + lane * 4);
  const float4 q1 = *(const float4*)(qb + 1 * 256 + lane * 4);
  const float4 q2 = *(const float4*)(qb + 2 * 256 + lane * 4);
  const float4 q3 = *(const float4*)(qb + 3 * 256 + lane * 4);

  float m = -INFINITY, l = 0.f;
  for (int s = srow0; s < srow0 + ROWS_PER_WAVE; s += 2) {
    const float* r0 = kb + (size_t)s * H;
    const float* r1 = kb + (size_t)(s + 1) * H;
    const float4 a0 = *(const float4*)(r0 + 0 * 256 + lane * 4);
    const float4 a1 = *(const float4*)(r0 + 1 * 256 + lane * 4);
    const float4 a2 = *(const float4*)(r0 + 2 * 256 + lane * 4);
    const float4 a3 = *(const float4*)(r0 + 3 * 256 + lane * 4);
    const float4 b0 = *(const float4*)(r1 + 0 * 256 + lane * 4);
    const float4 b1 = *(const float4*)(r1 + 1 * 256 + lane * 4);
    const float4 b2 = *(const float4*)(r1 + 2 * 256 + lane * 4);
    const float4 b3 = *(const float4*)(r1 + 3 * 256 + lane * 4);
    float d0 = dot4(a0, q0) + dot4(a1, q1) + dot4(a2, q2) + dot4(a3, q3);
    float d1 = dot4(b0, q0) + dot4(b1, q1) + dot4(b2, q2) + dot4(b3, q3);
#pragma unroll
    for (int off = 1; off < 64; off <<= 1) {
      d0 += __shfl_xor(d0, off);
      d1 += __shfl_xor(d1, off);
    }
    d0 *= SCALE; d1 *= SCALE;
    if (lane == 0) {
      out_attn[(size_t)b * S + s]     = d0;
      out_attn[(size_t)b * S + s + 1] = d1;
    }
    const float mn = fmaxf(m, fmaxf(d0, d1));
    l = l * __expf(m - mn) + __expf(d0 - mn) + __expf(d1 - mn);
    m = mn;
  }
  __shared__ float wm[4], wl[4];
  if (lane == 0) { wm[wave] = m; wl[wave] = l; }
  __syncthreads();
  if (t == 0) {
    const float M = fmaxf(fmaxf(wm[0], wm[1]), fmaxf(wm[2], wm[3]));
    const float L = wl[0] * __expf(wm[0] - M) + wl[1] * __expf(wm[1] - M) +
                    wl[2] * __expf(wm[2] - M) + wl[3] * __expf(wm[3] - M);
    ws[WS_ML + ((size_t)b * NC + c) * 2 + 0] = M;
    ws[WS_ML + ((size_t)b * NC + c) * 2 + 1] = L;
  }
}

__global__ __launch_bounds__(64) void k2b_merge(float* __restrict__ ws) {
  const int b = blockIdx.x;
  const int lane = threadIdx.x;
  float m = -INFINITY, l = 0.f;
  if (lane < NC) {
    m = ws[WS_ML + ((size_t)b * NC + lane) * 2 + 0];
    l = ws[WS_ML + ((size_t)b * NC + lane) * 2 + 1];
  }
  float M = m;
#pragma unroll
  for (int off = 1; off < 64; off <<= 1) M = fmaxf(M, __shfl_xor(M, off));
  float e = l * __expf(m - M);
#pragma unroll
  for (int off = 1; off < 64; off <<= 1) e += __shfl_xor(e, off);
  if (lane == 0) {
    ws[WS_MLG + b * 2 + 0] = M;
    ws[WS_MLG + b * 2 + 1] = e;
  }
}

__global__ __launch_bounds__(256) void k4b_values(
    const float* __restrict__ keys, const float* __restrict__ attn,
    float* __restrict__ out_values) {
  const int b   = blockIdx.x / ND4;
  const int dsl = blockIdx.x % ND4;
  const int t = threadIdx.x;
  const int r = t >> 6;
  const int cc = t & 63;
  const float* kb = keys + (size_t)b * S * H + (size_t)dsl * 64 + cc;
  const float* ab = attn + (size_t)b * S;
  float acc = 0.f;
  for (int s0 = r; s0 < S; s0 += 64) {
    float kv[16], av[16];
#pragma unroll
    for (int u = 0; u < 16; ++u) {
      const int s = s0 + 4 * u;
      kv[u] = kb[(size_t)s * H];
      av[u] = ab[s];
    }
#pragma unroll
    for (int u = 0; u < 16; ++u) acc = fmaf(av[u], kv[u], acc);
  }
  __shared__ float part[4][64];
  part[r][cc] = acc;
  __syncthreads();
  if (t < 64) {
    out_values[(size_t)b * H + (size_t)dsl * 64 + t] =
        part[0][t] + part[1][t] + part[2][t] + part[3][t];
  }
}

extern "C" void kernel_launch(void* const* d_in, const int* in_sizes, int n_in,
                              void* d_out, int out_size, void* d_ws, size_t ws_size,
                              hipStream_t stream) {
  const float* keys  = (const float*)d_in[0];
  const float* query = (const float*)d_in[1];
  float* out = (float*)d_out;
  float* ws  = (float*)d_ws;

  float* out_values = out;                  // [B, H]
  float* out_attn   = out + (size_t)B * H;  // [B, S, 1]

  if (ws_size >= WS_NEEDED_BYTES) {
    // single read of keys
    k1_fused<<<B * NC, 256, 0, stream>>>(keys, query, out_attn, ws);
    k2_combine<<<B, 256, 0, stream>>>(ws, out_values);
    k3_norm<<<(B * S) / 256, 256, 0, stream>>>(out_attn, ws);
  } else {
    // proven two-pass fallback (tiny ws)
    k1b_scores<<<B * NC, 256, 0, stream>>>(keys, query, out_attn, ws);
    k2b_merge<<<B, 64, 0, stream>>>(ws);
    k3_norm<<<(B * S) / 256, 256, 0, stream>>>(out_attn, ws);
    k4b_values<<<B * ND4, 256, 0, stream>>>(keys, out_attn, out_values);
  }
}

// Round 4
// 365.975 us; speedup vs baseline: 1.1012x; 1.0105x over previous
//
#include <hip/hip_runtime.h>
#include <math.h>

// keys [B,S,H] f32, query [B,H] f32, t unused.
// d_out = attn_values [B,H] (32768 f32) ++ attn [B,S,1] (65536 f32).
constexpr int B = 32, S = 2048, H = 1024;
constexpr float SCALE = 0.03125f;   // 1/sqrt(1024)

constexpr int NC = 32;              // s-chunks per batch
constexpr int SC = S / NC;          // 64 rows per chunk-block
constexpr int TILE = 8;             // rows per inner iteration

// ws layout (floats): ml [B*NC*2] | MLg [B*2] | o_chunks [B*NC*H]
constexpr size_t WS_ML  = 0;
constexpr size_t WS_MLG = WS_ML + (size_t)B * NC * 2;
constexpr size_t WS_O   = WS_MLG + (size_t)B * 2;
constexpr size_t WS_NEEDED_BYTES = (WS_O + (size_t)B * NC * H) * sizeof(float);

// ---------------- fast path: single read of keys ----------------
// One block per (b, chunk). Raw scores -> out_attn, (m,l) + weighted-key
// partial -> ws. Thread t owns d-cols [4t, 4t+4).
__global__ __launch_bounds__(256) void k1_fused(
    const float* __restrict__ keys, const float* __restrict__ query,
    float* __restrict__ out_attn, float* __restrict__ ws) {
  const int b = blockIdx.x / NC;
  const int c = blockIdx.x % NC;
  const int t = threadIdx.x;
  const int d0 = t * 4;
  const int wave = t >> 6, lane = t & 63;

  float* ml       = ws + WS_ML;
  float* o_chunks = ws + WS_O;

  const float* kb = keys + (size_t)b * S * H + (size_t)c * SC * H;
  const float4 q = *(const float4*)(query + (size_t)b * H + d0);

  float m = -INFINITY, l = 0.0f;
  float o0 = 0.f, o1 = 0.f, o2 = 0.f, o3 = 0.f;

  __shared__ float red[4][TILE];

  for (int s0 = 0; s0 < SC; s0 += TILE) {
    float4 k[TILE];
    float p[TILE];
#pragma unroll
    for (int j = 0; j < TILE; ++j) {
      k[j] = *(const float4*)(kb + (size_t)(s0 + j) * H + d0);
      p[j] = k[j].x * q.x + k[j].y * q.y + k[j].z * q.z + k[j].w * q.w;
    }
#pragma unroll
    for (int off = 32; off > 0; off >>= 1) {
#pragma unroll
      for (int j = 0; j < TILE; ++j) p[j] += __shfl_down(p[j], off);
    }
    if (lane == 0) {
#pragma unroll
      for (int j = 0; j < TILE; ++j) red[wave][j] = p[j];
    }
    __syncthreads();
    float snew[TILE];
    float mt = m;
#pragma unroll
    for (int j = 0; j < TILE; ++j) {
      snew[j] = (red[0][j] + red[1][j] + red[2][j] + red[3][j]) * SCALE;
      mt = fmaxf(mt, snew[j]);
    }
    if (t < TILE) out_attn[(size_t)b * S + c * SC + s0 + t] = snew[t];

    const float alpha = __expf(m - mt);
    float w[TILE];
    float lsum = 0.f;
#pragma unroll
    for (int j = 0; j < TILE; ++j) { w[j] = __expf(snew[j] - mt); lsum += w[j]; }
    l = l * alpha + lsum;
    o0 *= alpha; o1 *= alpha; o2 *= alpha; o3 *= alpha;
#pragma unroll
    for (int j = 0; j < TILE; ++j) {
      o0 += w[j] * k[j].x;
      o1 += w[j] * k[j].y;
      o2 += w[j] * k[j].z;
      o3 += w[j] * k[j].w;
    }
    m = mt;
    __syncthreads();
  }

  *(float4*)(o_chunks + ((size_t)b * NC + c) * H + d0) =
      make_float4(o0, o1, o2, o3);
  if (t == 0) {
    ml[((size_t)b * NC + c) * 2 + 0] = m;
    ml[((size_t)b * NC + c) * 2 + 1] = l;
  }
}

// Fused epilogue: 8 blocks per batch. Every block recomputes (M,L) from the
// tiny ml[] array (64 floats, L2-hot). Block i of batch b:
//   - threads 0..127: out_values cols [i*128, i*128+128) (combine 32 chunks)
//   - all 256 threads: normalize attn slice [i*256, i*256+256)
__global__ __launch_bounds__(256) void k23_epilogue(
    const float* __restrict__ ws, float* __restrict__ out_values,
    float* __restrict__ out_attn) {
  const int b = blockIdx.x >> 3;
  const int i = blockIdx.x & 7;
  const int t = threadIdx.x;

  const float* ml       = ws + WS_ML;
  const float* o_chunks = ws + WS_O;

  float M = -INFINITY;
#pragma unroll 4
  for (int c = 0; c < NC; ++c)
    M = fmaxf(M, ml[((size_t)b * NC + c) * 2 + 0]);
  float L = 0.f;
#pragma unroll 4
  for (int c = 0; c < NC; ++c) {
    const float mc = ml[((size_t)b * NC + c) * 2 + 0];
    const float lc = ml[((size_t)b * NC + c) * 2 + 1];
    L += lc * __expf(mc - M);
  }
  const float invL = 1.0f / L;

  if (t < 128) {
    const int col = i * 128 + t;
    float acc = 0.f;
    for (int c = 0; c < NC; ++c) {
      const float mc = ml[((size_t)b * NC + c) * 2 + 0];
      acc += __expf(mc - M) * o_chunks[((size_t)b * NC + c) * H + col];
    }
    out_values[(size_t)b * H + col] = acc * invL;
  }

  const size_t idx = (size_t)b * S + i * 256 + t;
  out_attn[idx] = __expf(out_attn[idx] - M) * invL;
}

// ---------------- fallback path (tiny ws; proven round-2) ----------------
constexpr int ROWS_PER_BLOCK = SC;                 // 64
constexpr int ROWS_PER_WAVE  = ROWS_PER_BLOCK / 4; // 16
constexpr int ND4 = 16;

__device__ __forceinline__ float dot4(const float4 a, const float4 q) {
  return a.x * q.x + a.y * q.y + a.z * q.z + a.w * q.w;
}

__global__ __launch_bounds__(256) void k1b_scores(
    const float* __restrict__ keys, const float* __restrict__ query,
    float* __restrict__ out_attn, float* __restrict__ ws) {
  const int b = blockIdx.x / NC;
  const int c = blockIdx.x % NC;
  const int t = threadIdx.x;
  const int wave = t >> 6, lane = t & 63;
  const int srow0 = c * ROWS_PER_BLOCK + wave * ROWS_PER_WAVE;

  const float* kb = keys + (size_t)b * S * H;
  const float* qb = query + (size_t)b * H;
  const float4 q0 = *(const float4*)(qb + 0 * 256 + lane * 4);
  const float4 q1 = *(const float4*)(qb + 1 * 256 + lane * 4);
  const float4 q2 = *(const float4*)(qb + 2 * 256 + lane * 4);
  const float4 q3 = *(const float4*)(qb + 3 * 256 + lane * 4);

  float m = -INFINITY, l = 0.f;
  for (int s = srow0; s < srow0 + ROWS_PER_WAVE; s += 2) {
    const float* r0 = kb + (size_t)s * H;
    const float* r1 = kb + (size_t)(s + 1) * H;
    const float4 a0 = *(const float4*)(r0 + 0 * 256 + lane * 4);
    const float4 a1 = *(const float4*)(r0 + 1 * 256 + lane * 4);
    const float4 a2 = *(const float4*)(r0 + 2 * 256 + lane * 4);
    const float4 a3 = *(const float4*)(r0 + 3 * 256 + lane * 4);
    const float4 b0 = *(const float4*)(r1 + 0 * 256 + lane * 4);
    const float4 b1 = *(const float4*)(r1 + 1 * 256 + lane * 4);
    const float4 b2 = *(const float4*)(r1 + 2 * 256 + lane * 4);
    const float4 b3 = *(const float4*)(r1 + 3 * 256 + lane * 4);
    float d0 = dot4(a0, q0) + dot4(a1, q1) + dot4(a2, q2) + dot4(a3, q3);
    float d1 = dot4(b0, q0) + dot4(b1, q1) + dot4(b2, q2) + dot4(b3, q3);
#pragma unroll
    for (int off = 1; off < 64; off <<= 1) {
      d0 += __shfl_xor(d0, off);
      d1 += __shfl_xor(d1, off);
    }
    d0 *= SCALE; d1 *= SCALE;
    if (lane == 0) {
      out_attn[(size_t)b * S + s]     = d0;
      out_attn[(size_t)b * S + s + 1] = d1;
    }
    const float mn = fmaxf(m, fmaxf(d0, d1));
    l = l * __expf(m - mn) + __expf(d0 - mn) + __expf(d1 - mn);
    m = mn;
  }
  __shared__ float wm[4], wl[4];
  if (lane == 0) { wm[wave] = m; wl[wave] = l; }
  __syncthreads();
  if (t == 0) {
    const float M = fmaxf(fmaxf(wm[0], wm[1]), fmaxf(wm[2], wm[3]));
    const float L = wl[0] * __expf(wm[0] - M) + wl[1] * __expf(wm[1] - M) +
                    wl[2] * __expf(wm[2] - M) + wl[3] * __expf(wm[3] - M);
    ws[WS_ML + ((size_t)b * NC + c) * 2 + 0] = M;
    ws[WS_ML + ((size_t)b * NC + c) * 2 + 1] = L;
  }
}

__global__ __launch_bounds__(64) void k2b_merge(float* __restrict__ ws) {
  const int b = blockIdx.x;
  const int lane = threadIdx.x;
  float m = -INFINITY, l = 0.f;
  if (lane < NC) {
    m = ws[WS_ML + ((size_t)b * NC + lane) * 2 + 0];
    l = ws[WS_ML + ((size_t)b * NC + lane) * 2 + 1];
  }
  float M = m;
#pragma unroll
  for (int off = 1; off < 64; off <<= 1) M = fmaxf(M, __shfl_xor(M, off));
  float e = l * __expf(m - M);
#pragma unroll
  for (int off = 1; off < 64; off <<= 1) e += __shfl_xor(e, off);
  if (lane == 0) {
    ws[WS_MLG + b * 2 + 0] = M;
    ws[WS_MLG + b * 2 + 1] = e;
  }
}

__global__ __launch_bounds__(256) void k3b_norm(
    float* __restrict__ out_attn, const float* __restrict__ ws) {
  const int i = blockIdx.x * 256 + threadIdx.x;
  const int b = i >> 11;  // S = 2048
  const float M = ws[WS_MLG + b * 2 + 0];
  const float invL = 1.0f / ws[WS_MLG + b * 2 + 1];
  out_attn[i] = __expf(out_attn[i] - M) * invL;
}

__global__ __launch_bounds__(256) void k4b_values(
    const float* __restrict__ keys, const float* __restrict__ attn,
    float* __restrict__ out_values) {
  const int b   = blockIdx.x / ND4;
  const int dsl = blockIdx.x % ND4;
  const int t = threadIdx.x;
  const int r = t >> 6;
  const int cc = t & 63;
  const float* kb = keys + (size_t)b * S * H + (size_t)dsl * 64 + cc;
  const float* ab = attn + (size_t)b * S;
  float acc = 0.f;
  for (int s0 = r; s0 < S; s0 += 64) {
    float kv[16], av[16];
#pragma unroll
    for (int u = 0; u < 16; ++u) {
      const int s = s0 + 4 * u;
      kv[u] = kb[(size_t)s * H];
      av[u] = ab[s];
    }
#pragma unroll
    for (int u = 0; u < 16; ++u) acc = fmaf(av[u], kv[u], acc);
  }
  __shared__ float part[4][64];
  part[r][cc] = acc;
  __syncthreads();
  if (t < 64) {
    out_values[(size_t)b * H + (size_t)dsl * 64 + t] =
        part[0][t] + part[1][t] + part[2][t] + part[3][t];
  }
}

extern "C" void kernel_launch(void* const* d_in, const int* in_sizes, int n_in,
                              void* d_out, int out_size, void* d_ws, size_t ws_size,
                              hipStream_t stream) {
  const float* keys  = (const float*)d_in[0];
  const float* query = (const float*)d_in[1];
  float* out = (float*)d_out;
  float* ws  = (float*)d_ws;

  float* out_values = out;                  // [B, H]
  float* out_attn   = out + (size_t)B * H;  // [B, S, 1]

  if (ws_size >= WS_NEEDED_BYTES) {
    k1_fused<<<B * NC, 256, 0, stream>>>(keys, query, out_attn, ws);
    k23_epilogue<<<B * 8, 256, 0, stream>>>(ws, out_values, out_attn);
  } else {
    k1b_scores<<<B * NC, 256, 0, stream>>>(keys, query, out_attn, ws);
    k2b_merge<<<B, 64, 0, stream>>>(ws);
    k3b_norm<<<(B * S) / 256, 256, 0, stream>>>(out_attn, ws);
    k4b_values<<<B * ND4, 256, 0, stream>>>(keys, out_attn, out_values);
  }
}